// Round 10
// baseline (153.402 us; speedup 1.0000x reference)
//
#include <hip/hip_runtime.h>
#include <stdint.h>

#define B_ 4
#define C_ 256
#define H_ 64
#define W_ 64
#define O_ 256
#define K_ 9
#define CK 2304     // K_*C_  (ck = k*256 + c, k-major)
#define HW 4096
#define NTOT 16384  // B_*HW

typedef __bf16 bf16x8 __attribute__((ext_vector_type(8)));
typedef __bf16 bf16x4 __attribute__((ext_vector_type(4)));
typedef float f32x4 __attribute__((ext_vector_type(4)));
typedef float f32x2 __attribute__((ext_vector_type(2)));
typedef f32x2 __attribute__((aligned(4))) f32x2u;

__device__ __forceinline__ uint16_t f2bf(float f) {
  uint32_t u = __builtin_bit_cast(uint32_t, f);
  return (uint16_t)((u + 0x7FFFu + ((u >> 16) & 1u)) >> 16);
}

__device__ __forceinline__ uint32_t pk_bf16(float a, float b) {
  uint16_t lo = __builtin_bit_cast(uint16_t, (__bf16)a);
  uint16_t hi = __builtin_bit_cast(uint16_t, (__bf16)b);
  return (uint32_t)lo | ((uint32_t)hi << 16);
}

// ======== kA v2 (R4/R7/R8-verified): weight converts | womb | zeros | xT transpose ====
__global__ void kA_prep(const float* __restrict__ weight, const float* __restrict__ w_om,
                        const float* __restrict__ x, uint16_t* __restrict__ wb,
                        uint16_t* __restrict__ womb, uint16_t* __restrict__ xT) {
  int bx = blockIdx.x;
  int t = threadIdx.x;
  if (bx < 256) {
    int o = bx, c = t;
    const float* wp = weight + (o * 256 + c) * 9;
#pragma unroll
    for (int k = 0; k < 9; ++k) wb[o * CK + k * 256 + c] = f2bf(wp[k]);
  } else if (bx < 283) {
    int j = bx - 256, c = t;  // j 0..26
    const float* wp = w_om + (j * 256 + c) * 9;
#pragma unroll
    for (int k = 0; k < 9; ++k) womb[j * CK + k * 256 + c] = f2bf(wp[k]);
  } else if (bx < 288) {
    int j = 27 + (bx - 283), c = t;  // zero rows 27..31 (row 31 = zrow)
#pragma unroll
    for (int k = 0; k < 9; ++k) womb[j * CK + k * 256 + c] = 0;
  } else {
    int bxl = bx - 288;
    int ct = bxl & 3;
    int hwt = (bxl >> 2) & 63;
    int b = bxl >> 8;
    int l = t & 63;
    int cq = t >> 6;

    __shared__ __align__(16) uint16_t tile[64 * 72];

    const float* xb = x + ((b * 256 + ct * 64) * HW) + hwt * 64;
#pragma unroll
    for (int i = 0; i < 16; ++i) {
      int c = cq * 16 + i;
      tile[l * 72 + c] = f2bf(xb[c * HW + l]);
    }
    __syncthreads();

    int hw = t >> 2;
    int c8 = (t & 3) * 8;
    uint16_t* dst = xT + ((size_t)b << 20) + (size_t)(hwt * 64 + hw) * 256 + ct * 64;
    *(uint4*)&dst[c8] = *(const uint4*)&tile[hw * 72 + c8];
    *(uint4*)&dst[c8 + 32] = *(const uint4*)&tile[hw * 72 + c8 + 32];
  }
}

// ======== k123 v4: R8 body + T4 counted-vmcnt segment barriers (triple-buffered As).
// Per segment: stage As[(g+2)%3] (4x global_load_lds), mma on As[g%3], then
// s_waitcnt vmcnt(4) lgkmcnt(0) + raw s_barrier (loads stay in flight across the
// barrier; in-order vmcnt retirement guarantees the 2-ahead buffer has landed).
// Slab-boundary gather regions keep full __syncthreads (safe drain, 8x).
// Wait ledger: seg g wait leaves only g's 4 loads outstanding; prologue vmcnt(0);
// tail segments g=34,35 (no stage) use vmcnt(0). sched_barrier(0) after each raw
// barrier prevents ds_read hoisting (rule #18). All else byte-identical to R8.

struct GatherState {
  float wa0[4], wb0[4], wa1[4], wb1[4];
  bf16x4 r00[4], r01[4], r10[4], r11[4];
};

__device__ __forceinline__ void gather_issue(GatherState& S, const uint16_t* __restrict__ xb,
                                             const float* pypx_l,  // LDS [3][9][64]
                                             int kg, int rbase, int lane) {
#pragma unroll
  for (int j = 0; j < 4; ++j) {
    int nrow = rbase + j;
    float py = pypx_l[(0 * 9 + kg) * 64 + nrow];
    float px = pypx_l[(1 * 9 + kg) * 64 + nrow];
    float mk = pypx_l[(2 * 9 + kg) * 64 + nrow];
    float fy0 = floorf(py), fx0 = floorf(px);
    float ly = py - fy0, lx = px - fx0;
    int y0 = (int)fy0, x0 = (int)fx0;
    bool vy0 = ((unsigned)y0 < 64u), vy1 = ((unsigned)(y0 + 1) < 64u);
    bool vx0 = ((unsigned)x0 < 64u), vx1 = ((unsigned)(x0 + 1) < 64u);
    float w00 = (vy0 && vx0) ? (1.f - ly) * (1.f - lx) * mk : 0.f;
    float w01 = (vy0 && vx1) ? (1.f - ly) * lx * mk : 0.f;
    float w10 = (vy1 && vx0) ? ly * (1.f - lx) * mk : 0.f;
    float w11 = (vy1 && vx1) ? ly * lx * mk : 0.f;
    bool sel0 = (x0 >= 63);
    bool sel1 = (x0 >= 0);
    S.wa0[j] = (sel0 ? 0.f : w00) + (sel1 ? 0.f : w01);
    S.wb0[j] = (sel0 ? w00 : 0.f) + (sel1 ? w01 : 0.f);
    S.wa1[j] = (sel0 ? 0.f : w10) + (sel1 ? 0.f : w11);
    S.wb1[j] = (sel0 ? w10 : 0.f) + (sel1 ? w11 : 0.f);
    int bx0 = min(max(x0, 0), 62);
    int a0 = min(max(y0, 0), 63) * 64 + bx0;
    int a1 = min(max(y0 + 1, 0), 63) * 64 + bx0;
    S.r00[j] = *(const bf16x4*)&xb[a0 * 256 + lane * 4];
    S.r01[j] = *(const bf16x4*)&xb[a0 * 256 + 256 + lane * 4];
    S.r10[j] = *(const bf16x4*)&xb[a1 * 256 + lane * 4];
    S.r11[j] = *(const bf16x4*)&xb[a1 * 256 + 256 + lane * 4];
  }
}

__device__ __forceinline__ void gather_finish(const GatherState& S, uint16_t* bslab,
                                              int rbase, int lane) {
#pragma unroll
  for (int j = 0; j < 4; ++j) {
    int nrow = rbase + j;
    float v[4];
#pragma unroll
    for (int i = 0; i < 4; ++i)
      v[i] = S.wa0[j] * (float)S.r00[j][i] + S.wb0[j] * (float)S.r01[j][i] +
             S.wa1[j] * (float)S.r10[j][i] + S.wb1[j] * (float)S.r11[j][i];
    uint2 pk;
    pk.x = pk_bf16(v[0], v[1]);
    pk.y = pk_bf16(v[2], v[3]);
    int chunk = lane >> 1;                               // 0..31 (8-elem chunks)
    int chs = (chunk & 24) | ((chunk & 7) ^ (nrow & 7)); // XOR swizzle, involution
    *(uint2*)&bslab[nrow * 256 + chs * 8 + (lane & 1) * 4] = pk;
  }
}

__device__ __forceinline__ void stageA(const uint16_t* __restrict__ wb, uint16_t* asbuf,
                                       int kbase, int t) {
#pragma unroll
  for (int i = 0; i < 4; ++i) {
    int rr = i * 64 + (t >> 3);
    const uint16_t* src = wb + rr * CK + kbase + (((t & 7) ^ (rr & 7)) << 3);
    __builtin_amdgcn_global_load_lds(
        (const __attribute__((address_space(1))) uint32_t*)src,
        (__attribute__((address_space(3))) uint32_t*)&asbuf[i * 4096 + t * 8], 16, 0, 0);
  }
}

__device__ __forceinline__ void mma_step(const uint16_t* AsP, const uint16_t* BsP,
                                         f32x4 acc[4][2], int wm, int wn, int lr, int q,
                                         int kt2) {
#pragma unroll
  for (int kc = 0; kc < 2; ++kc) {
    bf16x8 aF[4], bF[2];
#pragma unroll
    for (int i = 0; i < 4; ++i) {
      int row = wm * 64 + i * 16 + lr;
      aF[i] = *(const bf16x8*)&AsP[row * 64 + (((kc * 4 + q) ^ (row & 7)) << 3)];
    }
#pragma unroll
    for (int j = 0; j < 2; ++j) {
      int row = wn * 32 + j * 16 + lr;
      int kidx = kt2 * 8 + kc * 4 + q;  // 0..31
      int chs = (kidx & 24) | ((kidx & 7) ^ (row & 7));
      bF[j] = *(const bf16x8*)&BsP[row * 256 + chs * 8];
    }
#pragma unroll
    for (int i = 0; i < 4; ++i)
#pragma unroll
      for (int j = 0; j < 2; ++j)
        acc[i][j] = __builtin_amdgcn_mfma_f32_16x16x32_bf16(aF[i], bF[j], acc[i][j], 0, 0, 0);
  }
}

__global__ __launch_bounds__(512, 2) void k123(const uint16_t* __restrict__ wb,
                                               const uint16_t* __restrict__ womb,
                                               const uint16_t* __restrict__ xT,
                                               const float* __restrict__ b_om,
                                               const float* __restrict__ bias,
                                               float* __restrict__ out) {
  __shared__ __align__(16) uint16_t As[3][16384];  // 3 x 32 KB (triple buffer)
  __shared__ __align__(16) uint16_t Bs[16384];     // 32 KB (single buffer, R8 pattern)
  __shared__ float pypx_l[3 * 9 * 64];             // 6.75 KB: [py|px|mk][k][nn]

  int t = threadIdx.x;
  int lane = t & 63;
  int wid = __builtin_amdgcn_readfirstlane(t >> 6);
  int lr = lane & 15, q = lane >> 4;
  int bx = blockIdx.x;
  int swz = (bx & 7) * 32 + (bx >> 3);  // bijective XCD swizzle (256 % 8 == 0)
  int n0 = swz * 64;
  int b = n0 >> 12;
  int hw0 = n0 & 4095;
  const uint16_t* xb = xT + ((size_t)b << 20);

  // ====== prologue (R8-verified): offset conv as LDS-staged GEMM -> pypx_l ======
  {
    uint16_t* Apro = As[0];  // 16 KB of As[0] used as [32 j][256 c]
    int jh = wid >> 2, ng = wid & 3;
    const uint16_t* zrow = womb + 31 * CK;  // 2304 zeros
    f32x4 accp = {0.f, 0.f, 0.f, 0.f};

    for (int k = 0; k < 9; ++k) {
      int dy = k / 3 - 1, dx = k - (k / 3) * 3 - 1;
      // stage A: womb k-slice, 2 shots x 512 thr x 16 B = 16 KB, coalesced
#pragma unroll
      for (int i = 0; i < 2; ++i) {
        int id = i * 512 + t;
        int row = id >> 5, c5 = id & 31;
        int cs = (c5 & 24) | ((c5 & 7) ^ (row & 7));
        const uint16_t* src = womb + row * CK + k * 256 + cs * 8;
        __builtin_amdgcn_global_load_lds(
            (const __attribute__((address_space(1))) uint32_t*)src,
            (__attribute__((address_space(3))) uint32_t*)&Apro[row * 256 + c5 * 8], 16, 0, 0);
      }
      // stage B: identity-offset patch slab, 4 shots x 8 KB = 32 KB, coalesced
#pragma unroll
      for (int i = 0; i < 4; ++i) {
        int id = i * 512 + t;
        int nrow = id >> 5, c5 = id & 31;
        int hw = (n0 + nrow) & 4095;
        int y = hw >> 6, xx = hw & 63;
        int ny = y + dy, nx = xx + dx;
        bool valid = ((unsigned)ny < 64u) && ((unsigned)nx < 64u);
        int row_g = (ny << 6) + nx;
        int cs = (c5 & 24) | ((c5 & 7) ^ (nrow & 7));
        const uint16_t* src = valid ? (xb + row_g * 256 + cs * 8) : (zrow + cs * 8);
        __builtin_amdgcn_global_load_lds(
            (const __attribute__((address_space(1))) uint32_t*)src,
            (__attribute__((address_space(3))) uint32_t*)&Bs[nrow * 256 + c5 * 8], 16, 0, 0);
      }
      __syncthreads();
      // 8 MFMA: j-tile jh (16 j) x n-tile ng (16 n), K=256 over c
#pragma unroll
      for (int kt = 0; kt < 8; ++kt) {
        int kidx = kt * 4 + q;
        int arow = jh * 16 + lr;
        int achs = (kidx & 24) | ((kidx & 7) ^ (arow & 7));
        bf16x8 aF = *(const bf16x8*)&Apro[arow * 256 + achs * 8];
        int brow = ng * 16 + lr;
        int bchs = (kidx & 24) | ((kidx & 7) ^ (brow & 7));
        bf16x8 bF = *(const bf16x8*)&Bs[brow * 256 + bchs * 8];
        accp = __builtin_amdgcn_mfma_f32_16x16x32_bf16(aF, bF, accp, 0, 0, 0);
      }
      __syncthreads();
    }

    // write py/px/mk for own (j-tile, n-tile): j = jh*16 + q*4 + r, n = ng*16 + lr
    int nn = ng * 16 + lr;
    int hwp = (n0 + nn) & 4095;
    int yp = hwp >> 6, xp = hwp & 63;
#pragma unroll
    for (int r = 0; r < 4; ++r) {
      int j = jh * 16 + q * 4 + r;
      if (j < 27) {
        float v = accp[r] + b_om[j];
        if (j < 18) {
          int k = j >> 1;
          if ((j & 1) == 0)
            pypx_l[(0 * 9 + k) * 64 + nn] = (float)(yp - 1 + k / 3) + v;
          else
            pypx_l[(1 * 9 + k) * 64 + nn] = (float)(xp - 1 + k % 3) + v;
        } else {
          pypx_l[(2 * 9 + (j - 18)) * 64 + nn] = 1.f / (1.f + __expf(-v));
        }
      }
    }
    __syncthreads();
  }

  // ============ phase C: fused gather + GEMM, counted-vmcnt segments ============
  f32x4 acc[4][2];
  const f32x4 zero = {0.f, 0.f, 0.f, 0.f};
#pragma unroll
  for (int i = 0; i < 4; ++i)
#pragma unroll
    for (int j = 0; j < 2; ++j) acc[i][j] = zero;

  int wm = wid >> 1, wn = wid & 1;
  GatherState S;
  int wrow = wid * 8;  // this wave's 8 gather rows

  // prologue: gather k=0 slab into Bs; stage g=0 (buf0) and g=1 (buf1)
  gather_issue(S, xb, pypx_l, 0, wrow, lane);
  gather_finish(S, Bs, wrow, lane);
  gather_issue(S, xb, pypx_l, 0, wrow + 4, lane);
  gather_finish(S, Bs, wrow + 4, lane);
  stageA(wb, As[0], 0, t);    // g=0: slab 0, sub 0
  stageA(wb, As[1], 64, t);   // g=1: slab 0, sub 1
  asm volatile("s_waitcnt vmcnt(0) lgkmcnt(0)" ::: "memory");
  __builtin_amdgcn_s_barrier();
  __builtin_amdgcn_sched_barrier(0);

  for (int k = 0; k < 9; ++k) {
    for (int s = 0; s < 4; ++s) {
      int g = k * 4 + s;
      // stage 2 segments ahead into As[(g+2)%3]
      bool dostage = (g + 2 <= 35);
      if (dostage) {
        int g2 = g + 2;
        int kb = (g2 >> 2) * 256 + (g2 & 3) * 64;
        stageA(wb, As[g2 % 3], kb, t);
      }
      __builtin_amdgcn_s_setprio(1);
      mma_step(As[g % 3], Bs, acc, wm, wn, lr, q, s);
      __builtin_amdgcn_s_setprio(0);
      if (s == 3 && k < 8) {
        // slab boundary: isolated gather region (full drain — always safe)
        __syncthreads();
        gather_issue(S, xb, pypx_l, k + 1, wrow, lane);
        gather_finish(S, Bs, wrow, lane);
        gather_issue(S, xb, pypx_l, k + 1, wrow + 4, lane);
        gather_finish(S, Bs, wrow + 4, lane);
        __syncthreads();
      } else {
        // T4: leave this segment's 4 loads in flight across the barrier
        if (dostage)
          asm volatile("s_waitcnt vmcnt(4) lgkmcnt(0)" ::: "memory");
        else
          asm volatile("s_waitcnt vmcnt(0) lgkmcnt(0)" ::: "memory");
        __builtin_amdgcn_s_barrier();
        __builtin_amdgcn_sched_barrier(0);
      }
    }
  }

  // epilogue (same fragment->C mapping as verified)
#pragma unroll
  for (int i = 0; i < 4; ++i) {
#pragma unroll
    for (int r = 0; r < 4; ++r) {
      int o = wm * 64 + i * 16 + q * 4 + r;
      float bv = bias[o];
      float* orow = out + (b * O_ + o) * HW + hw0;
#pragma unroll
      for (int j = 0; j < 2; ++j) orow[wn * 32 + j * 16 + lr] = acc[i][j][r] + bv;
    }
  }
}

// ================= fallback path (small workspace): fp32 pipeline =============
__global__ void k0_wconv(const float* __restrict__ weight, uint16_t* __restrict__ wb) {
  int idx = blockIdx.x * 256 + threadIdx.x;
  if (idx >= O_ * CK) return;
  int o = idx / CK;
  int rem = idx - o * CK;
  int k = rem >> 8;
  int c = rem & 255;
  wb[idx] = f2bf(weight[(o * C_ + c) * K_ + k]);
}

__global__ void k1_offconv(const float* __restrict__ x, const float* __restrict__ w_om,
                           const float* __restrict__ b_om, float* __restrict__ pypxmk) {
  int bx = blockIdx.x;
  int jq = bx % 7;
  int h = (bx / 7) % H_;
  int b = bx / (7 * H_);
  int t = threadIdx.x;
  int w = t & 63;
  int cs = __builtin_amdgcn_readfirstlane(t >> 6);

  float acc[4] = {0.f, 0.f, 0.f, 0.f};
  const float* xb = x + (b * C_) * HW;

  for (int ci = 0; ci < 64; ++ci) {
    int c = cs * 64 + ci;
    const float* xr = xb + c * HW;
    float xv[3][3];
#pragma unroll
    for (int r = 0; r < 3; ++r) {
      int y = h - 1 + r;
      bool yv = ((unsigned)y < 64u);
#pragma unroll
      for (int dx = 0; dx < 3; ++dx) {
        int xx = w - 1 + dx;
        bool v = yv && ((unsigned)xx < 64u);
        xv[r][dx] = v ? xr[y * 64 + xx] : 0.f;
      }
    }
    const float* wp = w_om + ((jq * 4) * C_ + c) * 9;
#pragma unroll
    for (int jj = 0; jj < 4; ++jj) {
      int j = jq * 4 + jj;
      int jeff = (j < 27) ? jj : 0;
      const float* wj = wp + jeff * (C_ * 9);
      float a = 0.f;
#pragma unroll
      for (int r = 0; r < 3; ++r)
#pragma unroll
        for (int dx = 0; dx < 3; ++dx)
          a = fmaf(xv[r][dx], wj[r * 3 + dx], a);
      acc[jj] += a;
    }
  }

  __shared__ float red[4][4][64];
#pragma unroll
  for (int jj = 0; jj < 4; ++jj) red[cs][jj][w] = acc[jj];
  __syncthreads();

  int jj = t >> 6;
  int j = jq * 4 + jj;
  if (j < 27) {
    float s = red[0][jj][w] + red[1][jj][w] + red[2][jj][w] + red[3][jj][w] + b_om[j];
    float* pyA = pypxmk;
    float* pxA = pypxmk + 147456;
    float* mkA = pypxmk + 294912;
    if (j < 18) {
      int k = j >> 1;
      int off = (b * 9 + k) * HW + h * 64 + w;
      if ((j & 1) == 0)
        pyA[off] = (float)(h - 1 + k / 3) + s;
      else
        pxA[off] = (float)(w - 1 + k % 3) + s;
    } else {
      int k = j - 18;
      mkA[(b * 9 + k) * HW + h * 64 + w] = 1.f / (1.f + __expf(-s));
    }
  }
}

__global__ void k2_fb(const float* __restrict__ x, const float* __restrict__ pypxmk,
                      uint16_t* __restrict__ cols) {
  int bx = blockIdx.x;
  int cg2 = bx & 15;
  int h = (bx >> 4) & 63;
  int b = bx >> 10;
  int t = threadIdx.x;
  int w = t & 63;
  int g = t >> 6;

  const float* pyA = pypxmk;
  const float* pxA = pypxmk + 147456;
  const float* mkA = pypxmk + 294912;

  __shared__ uint16_t tile[64 * 146];
  const float* xb = x + b * C_ * HW;
  int cbase = cg2 * 16 + g * 4;

#pragma unroll
  for (int k = 0; k < 9; ++k) {
    int poff = (b * 9 + k) * HW + h * 64 + w;
    float py = pyA[poff];
    float px = pxA[poff];
    float mk = mkA[poff];
    float fy0 = floorf(py), fx0 = floorf(px);
    float ly = py - fy0, lx = px - fx0;
    int y0 = (int)fy0, x0 = (int)fx0;
    bool vy0 = ((unsigned)y0 < 64u), vy1 = ((unsigned)(y0 + 1) < 64u);
    bool vx0 = ((unsigned)x0 < 64u), vx1 = ((unsigned)(x0 + 1) < 64u);
    float w00 = (vy0 && vx0) ? (1.f - ly) * (1.f - lx) * mk : 0.f;
    float w01 = (vy0 && vx1) ? (1.f - ly) * lx * mk : 0.f;
    float w10 = (vy1 && vx0) ? ly * (1.f - lx) * mk : 0.f;
    float w11 = (vy1 && vx1) ? ly * lx * mk : 0.f;
    bool sel0 = (x0 >= 63);
    bool sel1 = (x0 >= 0);
    float wa0 = (sel0 ? 0.f : w00) + (sel1 ? 0.f : w01);
    float wb0 = (sel0 ? w00 : 0.f) + (sel1 ? w01 : 0.f);
    float wa1 = (sel0 ? 0.f : w10) + (sel1 ? 0.f : w11);
    float wb1 = (sel0 ? w10 : 0.f) + (sel1 ? w11 : 0.f);
    int bx0 = min(max(x0, 0), 62);
    int a0 = min(max(y0, 0), 63) * 64 + bx0;
    int a1 = min(max(y0 + 1, 0), 63) * 64 + bx0;

#pragma unroll
    for (int cp = 0; cp < 2; ++cp) {
      const float* xcA = xb + (cbase + cp * 2) * HW;
      const float* xcB = xcA + HW;
      f32x2 A0 = *(const f32x2u*)&xcA[a0];
      f32x2 A1 = *(const f32x2u*)&xcA[a1];
      f32x2 B0 = *(const f32x2u*)&xcB[a0];
      f32x2 B1 = *(const f32x2u*)&xcB[a1];
      float rA = wa0 * A0.x + wb0 * A0.y + wa1 * A1.x + wb1 * A1.y;
      float rB = wa0 * B0.x + wb0 * B0.y + wa1 * B1.x + wb1 * B1.y;
      *(uint32_t*)&tile[w * 146 + k * 16 + g * 4 + cp * 2] = pk_bf16(rA, rB);
    }
  }
  __syncthreads();

#pragma unroll
  for (int it = 0; it < 18; ++it) {
    int u = t + it * 256;
    int wu = u / 72;
    int rem = u - wu * 72;
    int k = rem >> 3;
    int cd = rem & 7;
    uint32_t val = *(const uint32_t*)&tile[wu * 146 + rem * 2];
    int n = b * HW + h * 64 + wu;
    int dst = n * CK + k * 256 + cg2 * 16 + cd * 2;
    *(uint32_t*)&cols[dst] = val;
  }
}

__global__ void k3_flex(const uint16_t* __restrict__ wb, const uint16_t* __restrict__ cols,
                        const float* __restrict__ bias, float* __restrict__ out) {
  int bx = blockIdx.x;
  int mt = bx & 1;
  int nt = bx >> 1;
  int o0 = mt * 128;
  int n0 = nt * 128;
  int t = threadIdx.x;
  int lane = t & 63;
  int wid = t >> 6;
  int wm = wid >> 1, wn = wid & 1;
  int lr = lane & 15, q = lane >> 4;

  __shared__ __align__(16) uint16_t As[128 * 32];
  __shared__ __align__(16) uint16_t Bs[128 * 32];

  f32x4 acc[4][4];
  const f32x4 zero = {0.f, 0.f, 0.f, 0.f};
#pragma unroll
  for (int i = 0; i < 4; ++i)
#pragma unroll
    for (int j = 0; j < 4; ++j) acc[i][j] = zero;

  int r0 = t >> 2;
  int koff = (t & 3) * 8;
  const uint16_t* gA = wb + (o0 + r0) * CK + koff;
  const uint16_t* gB = cols + (n0 + r0) * CK + koff;

  for (int kt = 0; kt < 72; ++kt) {
    int k0 = kt * 32;
    __builtin_amdgcn_global_load_lds(
        (const __attribute__((address_space(1))) uint32_t*)(gA + k0),
        (__attribute__((address_space(3))) uint32_t*)&As[t * 8], 16, 0, 0);
    __builtin_amdgcn_global_load_lds(
        (const __attribute__((address_space(1))) uint32_t*)(gA + 64 * CK + k0),
        (__attribute__((address_space(3))) uint32_t*)&As[2048 + t * 8], 16, 0, 0);
    __builtin_amdgcn_global_load_lds(
        (const __attribute__((address_space(1))) uint32_t*)(gB + k0),
        (__attribute__((address_space(3))) uint32_t*)&Bs[t * 8], 16, 0, 0);
    __builtin_amdgcn_global_load_lds(
        (const __attribute__((address_space(1))) uint32_t*)(gB + 64 * CK + k0),
        (__attribute__((address_space(3))) uint32_t*)&Bs[2048 + t * 8], 16, 0, 0);
    __syncthreads();

    bf16x8 aF[4], bF[4];
#pragma unroll
    for (int i = 0; i < 4; ++i)
      aF[i] = *(const bf16x8*)&As[(wm * 64 + i * 16 + lr) * 32 + q * 8];
#pragma unroll
    for (int j = 0; j < 4; ++j)
      bF[j] = *(const bf16x8*)&Bs[(wn * 64 + j * 16 + lr) * 32 + q * 8];
#pragma unroll
    for (int i = 0; i < 4; ++i)
#pragma unroll
      for (int j = 0; j < 4; ++j)
        acc[i][j] = __builtin_amdgcn_mfma_f32_16x16x32_bf16(aF[i], bF[j], acc[i][j], 0, 0, 0);
    __syncthreads();
  }

  int bb = n0 >> 12;
  int hw0 = n0 & 4095;
#pragma unroll
  for (int i = 0; i < 4; ++i) {
#pragma unroll
    for (int r = 0; r < 4; ++r) {
      int o = o0 + wm * 64 + i * 16 + q * 4 + r;
      float bv = bias[o];
      float* orow = out + (bb * O_ + o) * HW + hw0;
#pragma unroll
      for (int j = 0; j < 4; ++j) orow[wn * 64 + j * 16 + lr] = acc[i][j][r] + bv;
    }
  }
}

extern "C" void kernel_launch(void* const* d_in, const int* in_sizes, int n_in,
                              void* d_out, int out_size, void* d_ws, size_t ws_size,
                              hipStream_t stream) {
  const float* x = (const float*)d_in[0];
  const float* w_om = (const float*)d_in[1];
  const float* b_om = (const float*)d_in[2];
  const float* weight = (const float*)d_in[3];
  const float* bias = (const float*)d_in[4];
  float* out = (float*)d_out;

  char* ws = (char*)d_ws;
  uint16_t* wb = (uint16_t*)ws;                   // 1,179,648 B
  uint16_t* womb = (uint16_t*)(ws + 1179648);     // 147,456 B    -> 1,327,104
  uint16_t* xT = (uint16_t*)(ws + 1327104);       // 8,388,608 B  -> 9,715,712

  if (ws_size >= 11485184ull) {
    // 2-dispatch pipeline: prep -> fused {offset conv + gather + GEMM}
    hipLaunchKernelGGL(kA_prep, dim3(1312), dim3(256), 0, stream, weight, w_om, x, wb, womb, xT);
    hipLaunchKernelGGL(k123, dim3(256), dim3(512), 0, stream, wb, womb, xT, b_om, bias, out);
  } else {
    // fallback: fp32 pipeline + single-pass GEMM (needs 78.4 MB)
    float* pypx_fb = (float*)(ws + 1179648);
    uint16_t* colsf = (uint16_t*)(ws + 2949120);
    hipLaunchKernelGGL(k0_wconv, dim3(2304), dim3(256), 0, stream, weight, wb);
    hipLaunchKernelGGL(k1_offconv, dim3(4 * 64 * 7), dim3(256), 0, stream, x, w_om, b_om, pypx_fb);
    hipLaunchKernelGGL(k2_fb, dim3(4 * 64 * 16), dim3(256), 0, stream, x, pypx_fb, colsf);
    hipLaunchKernelGGL(k3_flex, dim3(256), dim3(256), 0, stream, wb, colsf, bias, out);
  }
}

// Round 11
// 149.476 us; speedup vs baseline: 1.0263x; 1.0263x over previous
//
#include <hip/hip_runtime.h>
#include <stdint.h>

#define B_ 4
#define C_ 256
#define H_ 64
#define W_ 64
#define O_ 256
#define K_ 9
#define CK 2304     // K_*C_  (ck = k*256 + c, k-major)
#define HW 4096
#define NTOT 16384  // B_*HW

typedef __bf16 bf16x8 __attribute__((ext_vector_type(8)));
typedef __bf16 bf16x4 __attribute__((ext_vector_type(4)));
typedef float f32x4 __attribute__((ext_vector_type(4)));
typedef float f32x2 __attribute__((ext_vector_type(2)));
typedef f32x2 __attribute__((aligned(4))) f32x2u;

__device__ __forceinline__ uint16_t f2bf(float f) {
  uint32_t u = __builtin_bit_cast(uint32_t, f);
  return (uint16_t)((u + 0x7FFFu + ((u >> 16) & 1u)) >> 16);
}

__device__ __forceinline__ uint32_t pk_bf16(float a, float b) {
  uint16_t lo = __builtin_bit_cast(uint16_t, (__bf16)a);
  uint16_t hi = __builtin_bit_cast(uint16_t, (__bf16)b);
  return (uint32_t)lo | ((uint32_t)hi << 16);
}

// ======== kA v2 (R4/R7/R8-verified): weight converts | womb | zeros | xT transpose ====
__global__ void kA_prep(const float* __restrict__ weight, const float* __restrict__ w_om,
                        const float* __restrict__ x, uint16_t* __restrict__ wb,
                        uint16_t* __restrict__ womb, uint16_t* __restrict__ xT) {
  int bx = blockIdx.x;
  int t = threadIdx.x;
  if (bx < 256) {
    int o = bx, c = t;
    const float* wp = weight + (o * 256 + c) * 9;
#pragma unroll
    for (int k = 0; k < 9; ++k) wb[o * CK + k * 256 + c] = f2bf(wp[k]);
  } else if (bx < 283) {
    int j = bx - 256, c = t;  // j 0..26
    const float* wp = w_om + (j * 256 + c) * 9;
#pragma unroll
    for (int k = 0; k < 9; ++k) womb[j * CK + k * 256 + c] = f2bf(wp[k]);
  } else if (bx < 288) {
    int j = 27 + (bx - 283), c = t;  // zero rows 27..31 (row 31 = zrow)
#pragma unroll
    for (int k = 0; k < 9; ++k) womb[j * CK + k * 256 + c] = 0;
  } else {
    int bxl = bx - 288;
    int ct = bxl & 3;
    int hwt = (bxl >> 2) & 63;
    int b = bxl >> 8;
    int l = t & 63;
    int cq = t >> 6;

    __shared__ __align__(16) uint16_t tile[64 * 72];

    const float* xb = x + ((b * 256 + ct * 64) * HW) + hwt * 64;
#pragma unroll
    for (int i = 0; i < 16; ++i) {
      int c = cq * 16 + i;
      tile[l * 72 + c] = f2bf(xb[c * HW + l]);
    }
    __syncthreads();

    int hw = t >> 2;
    int c8 = (t & 3) * 8;
    uint16_t* dst = xT + ((size_t)b << 20) + (size_t)(hwt * 64 + hw) * 256 + ct * 64;
    *(uint4*)&dst[c8] = *(const uint4*)&tile[hw * 72 + c8];
    *(uint4*)&dst[c8 + 32] = *(const uint4*)&tile[hw * 72 + c8 + 32];
  }
}

// ======== k123 v5: R8 body with BK=128 single-buffer As (fewer phase boundaries).
// Per slab: {mma half0 -> sync -> stage half1 -> sync -> mma half1 -> sync ->
// gather(k+1)+stage(k+1 half0) -> sync} = 4 boundaries/slab vs R8's 6. Each MFMA
// phase is 2x deeper (32 MFMA, 24 ds_reads) amortizing per-boundary chain latency.
// As [256][128]: stage dest linear (base+lane*16B), source pre-swizzled with
// sigma(c)=(c&8)|((c&7)^(row&7)); read applies same involution (rule #21); A-read
// bank spread = 2-way (free). Bs/gather/prologue/epilogue identical to R8-verified.

struct GatherState {
  float wa0[4], wb0[4], wa1[4], wb1[4];
  bf16x4 r00[4], r01[4], r10[4], r11[4];
};

__device__ __forceinline__ void gather_issue(GatherState& S, const uint16_t* __restrict__ xb,
                                             const float* pypx_l,  // LDS [3][9][64]
                                             int kg, int rbase, int lane) {
#pragma unroll
  for (int j = 0; j < 4; ++j) {
    int nrow = rbase + j;
    float py = pypx_l[(0 * 9 + kg) * 64 + nrow];
    float px = pypx_l[(1 * 9 + kg) * 64 + nrow];
    float mk = pypx_l[(2 * 9 + kg) * 64 + nrow];
    float fy0 = floorf(py), fx0 = floorf(px);
    float ly = py - fy0, lx = px - fx0;
    int y0 = (int)fy0, x0 = (int)fx0;
    bool vy0 = ((unsigned)y0 < 64u), vy1 = ((unsigned)(y0 + 1) < 64u);
    bool vx0 = ((unsigned)x0 < 64u), vx1 = ((unsigned)(x0 + 1) < 64u);
    float w00 = (vy0 && vx0) ? (1.f - ly) * (1.f - lx) * mk : 0.f;
    float w01 = (vy0 && vx1) ? (1.f - ly) * lx * mk : 0.f;
    float w10 = (vy1 && vx0) ? ly * (1.f - lx) * mk : 0.f;
    float w11 = (vy1 && vx1) ? ly * lx * mk : 0.f;
    bool sel0 = (x0 >= 63);
    bool sel1 = (x0 >= 0);
    S.wa0[j] = (sel0 ? 0.f : w00) + (sel1 ? 0.f : w01);
    S.wb0[j] = (sel0 ? w00 : 0.f) + (sel1 ? w01 : 0.f);
    S.wa1[j] = (sel0 ? 0.f : w10) + (sel1 ? 0.f : w11);
    S.wb1[j] = (sel0 ? w10 : 0.f) + (sel1 ? w11 : 0.f);
    int bx0 = min(max(x0, 0), 62);
    int a0 = min(max(y0, 0), 63) * 64 + bx0;
    int a1 = min(max(y0 + 1, 0), 63) * 64 + bx0;
    S.r00[j] = *(const bf16x4*)&xb[a0 * 256 + lane * 4];
    S.r01[j] = *(const bf16x4*)&xb[a0 * 256 + 256 + lane * 4];
    S.r10[j] = *(const bf16x4*)&xb[a1 * 256 + lane * 4];
    S.r11[j] = *(const bf16x4*)&xb[a1 * 256 + 256 + lane * 4];
  }
}

__device__ __forceinline__ void gather_finish(const GatherState& S, uint16_t* bslab,
                                              int rbase, int lane) {
#pragma unroll
  for (int j = 0; j < 4; ++j) {
    int nrow = rbase + j;
    float v[4];
#pragma unroll
    for (int i = 0; i < 4; ++i)
      v[i] = S.wa0[j] * (float)S.r00[j][i] + S.wb0[j] * (float)S.r01[j][i] +
             S.wa1[j] * (float)S.r10[j][i] + S.wb1[j] * (float)S.r11[j][i];
    uint2 pk;
    pk.x = pk_bf16(v[0], v[1]);
    pk.y = pk_bf16(v[2], v[3]);
    int chunk = lane >> 1;                               // 0..31 (8-elem chunks)
    int chs = (chunk & 24) | ((chunk & 7) ^ (nrow & 7)); // XOR swizzle, involution
    *(uint2*)&bslab[nrow * 256 + chs * 8 + (lane & 1) * 4] = pk;
  }
}

// stage wb[0..255][kbase..kbase+127] into As[256][128]; 8 shots x 512 thr x 16 B.
// Dest linear per lane; source chunk pre-swizzled with the same involution the
// reader applies: sigma(c) = (c&8) | ((c&7) ^ (row&7)).
__device__ __forceinline__ void stageA128(const uint16_t* __restrict__ wb, uint16_t* asbuf,
                                          int kbase, int t) {
#pragma unroll
  for (int i = 0; i < 8; ++i) {
    int slot = i * 512 + t;
    int row = slot >> 4;       // 0..255
    int ch = slot & 15;        // 0..15
    int sc = (ch & 8) | ((ch & 7) ^ (row & 7));
    const uint16_t* src = wb + row * CK + kbase + sc * 8;
    __builtin_amdgcn_global_load_lds(
        (const __attribute__((address_space(1))) uint32_t*)src,
        (__attribute__((address_space(3))) uint32_t*)&asbuf[row * 128 + ch * 8], 16, 0, 0);
  }
}

// one K=128 half-slab of MFMA: 4 kc x (4 A + 2 B reads, 8 MFMA) = 32 MFMA.
__device__ __forceinline__ void mma128(const uint16_t* AsP, const uint16_t* BsP,
                                       f32x4 acc[4][2], int wm, int wn, int lr, int q,
                                       int khalf) {
#pragma unroll
  for (int kc = 0; kc < 4; ++kc) {
    bf16x8 aF[4], bF[2];
#pragma unroll
    for (int i = 0; i < 4; ++i) {
      int row = wm * 64 + i * 16 + lr;
      int ka = kc * 4 + q;  // 0..15 within the 128-col buffer
      int sch = (ka & 8) | ((ka & 7) ^ (row & 7));
      aF[i] = *(const bf16x8*)&AsP[row * 128 + sch * 8];
    }
#pragma unroll
    for (int j = 0; j < 2; ++j) {
      int row = wn * 32 + j * 16 + lr;
      int kidx = khalf * 16 + kc * 4 + q;  // 0..31 within the slab's 256 c
      int chs = (kidx & 24) | ((kidx & 7) ^ (row & 7));
      bF[j] = *(const bf16x8*)&BsP[row * 256 + chs * 8];
    }
#pragma unroll
    for (int i = 0; i < 4; ++i)
#pragma unroll
      for (int j = 0; j < 2; ++j)
        acc[i][j] = __builtin_amdgcn_mfma_f32_16x16x32_bf16(aF[i], bF[j], acc[i][j], 0, 0, 0);
  }
}

__global__ __launch_bounds__(512, 2) void k123(const uint16_t* __restrict__ wb,
                                               const uint16_t* __restrict__ womb,
                                               const uint16_t* __restrict__ xT,
                                               const float* __restrict__ b_om,
                                               const float* __restrict__ bias,
                                               float* __restrict__ out) {
  __shared__ __align__(16) uint16_t As[32768];  // 64 KB, [256][128] (single buffer)
  __shared__ __align__(16) uint16_t Bs[16384];  // 32 KB, [64][256]
  __shared__ float pypx_l[3 * 9 * 64];          // 6.75 KB: [py|px|mk][k][nn]

  int t = threadIdx.x;
  int lane = t & 63;
  int wid = __builtin_amdgcn_readfirstlane(t >> 6);
  int lr = lane & 15, q = lane >> 4;
  int bx = blockIdx.x;
  int swz = (bx & 7) * 32 + (bx >> 3);  // bijective XCD swizzle (256 % 8 == 0)
  int n0 = swz * 64;
  int b = n0 >> 12;
  int hw0 = n0 & 4095;
  const uint16_t* xb = xT + ((size_t)b << 20);

  // ====== prologue (R8-verified): offset conv as LDS-staged GEMM -> pypx_l ======
  {
    uint16_t* Apro = As;  // 16 KB of As used as [32 j][256 c]
    int jh = wid >> 2, ng = wid & 3;
    const uint16_t* zrow = womb + 31 * CK;  // 2304 zeros
    f32x4 accp = {0.f, 0.f, 0.f, 0.f};

    for (int k = 0; k < 9; ++k) {
      int dy = k / 3 - 1, dx = k - (k / 3) * 3 - 1;
      // stage A: womb k-slice, 2 shots x 512 thr x 16 B = 16 KB, coalesced
#pragma unroll
      for (int i = 0; i < 2; ++i) {
        int id = i * 512 + t;
        int row = id >> 5, c5 = id & 31;
        int cs = (c5 & 24) | ((c5 & 7) ^ (row & 7));
        const uint16_t* src = womb + row * CK + k * 256 + cs * 8;
        __builtin_amdgcn_global_load_lds(
            (const __attribute__((address_space(1))) uint32_t*)src,
            (__attribute__((address_space(3))) uint32_t*)&Apro[row * 256 + c5 * 8], 16, 0, 0);
      }
      // stage B: identity-offset patch slab, 4 shots x 8 KB = 32 KB, coalesced
#pragma unroll
      for (int i = 0; i < 4; ++i) {
        int id = i * 512 + t;
        int nrow = id >> 5, c5 = id & 31;
        int hw = (n0 + nrow) & 4095;
        int y = hw >> 6, xx = hw & 63;
        int ny = y + dy, nx = xx + dx;
        bool valid = ((unsigned)ny < 64u) && ((unsigned)nx < 64u);
        int row_g = (ny << 6) + nx;
        int cs = (c5 & 24) | ((c5 & 7) ^ (nrow & 7));
        const uint16_t* src = valid ? (xb + row_g * 256 + cs * 8) : (zrow + cs * 8);
        __builtin_amdgcn_global_load_lds(
            (const __attribute__((address_space(1))) uint32_t*)src,
            (__attribute__((address_space(3))) uint32_t*)&Bs[nrow * 256 + c5 * 8], 16, 0, 0);
      }
      __syncthreads();
      // 8 MFMA: j-tile jh (16 j) x n-tile ng (16 n), K=256 over c
#pragma unroll
      for (int kt = 0; kt < 8; ++kt) {
        int kidx = kt * 4 + q;
        int arow = jh * 16 + lr;
        int achs = (kidx & 24) | ((kidx & 7) ^ (arow & 7));
        bf16x8 aF = *(const bf16x8*)&Apro[arow * 256 + achs * 8];
        int brow = ng * 16 + lr;
        int bchs = (kidx & 24) | ((kidx & 7) ^ (brow & 7));
        bf16x8 bF = *(const bf16x8*)&Bs[brow * 256 + bchs * 8];
        accp = __builtin_amdgcn_mfma_f32_16x16x32_bf16(aF, bF, accp, 0, 0, 0);
      }
      __syncthreads();
    }

    // write py/px/mk for own (j-tile, n-tile): j = jh*16 + q*4 + r, n = ng*16 + lr
    int nn = ng * 16 + lr;
    int hwp = (n0 + nn) & 4095;
    int yp = hwp >> 6, xp = hwp & 63;
#pragma unroll
    for (int r = 0; r < 4; ++r) {
      int j = jh * 16 + q * 4 + r;
      if (j < 27) {
        float v = accp[r] + b_om[j];
        if (j < 18) {
          int k = j >> 1;
          if ((j & 1) == 0)
            pypx_l[(0 * 9 + k) * 64 + nn] = (float)(yp - 1 + k / 3) + v;
          else
            pypx_l[(1 * 9 + k) * 64 + nn] = (float)(xp - 1 + k % 3) + v;
        } else {
          pypx_l[(2 * 9 + (j - 18)) * 64 + nn] = 1.f / (1.f + __expf(-v));
        }
      }
    }
    __syncthreads();
  }

  // ============ phase C: fused gather + GEMM, BK=128, 4 boundaries/slab ============
  f32x4 acc[4][2];
  const f32x4 zero = {0.f, 0.f, 0.f, 0.f};
#pragma unroll
  for (int i = 0; i < 4; ++i)
#pragma unroll
    for (int j = 0; j < 2; ++j) acc[i][j] = zero;

  int wm = wid >> 1, wn = wid & 1;
  GatherState S;
  int wrow = wid * 8;  // this wave's 8 gather rows

  // prologue: gather k=0 slab into Bs; stage slab 0 half 0 into As
  gather_issue(S, xb, pypx_l, 0, wrow, lane);
  gather_finish(S, Bs, wrow, lane);
  gather_issue(S, xb, pypx_l, 0, wrow + 4, lane);
  gather_finish(S, Bs, wrow + 4, lane);
  stageA128(wb, As, 0, t);
  __syncthreads();

  for (int k = 0; k < 9; ++k) {
    // half 0 (As holds wb[:, k*256 .. k*256+127])
    mma128(As, Bs, acc, wm, wn, lr, q, 0);
    __syncthreads();
    // stage half 1 (overwrites As; all reads done at the sync above)
    stageA128(wb, As, k * 256 + 128, t);
    __syncthreads();
    mma128(As, Bs, acc, wm, wn, lr, q, 1);
    __syncthreads();
    // gather next slab (Bs reads complete) + stage next slab half 0
    if (k < 8) {
      gather_issue(S, xb, pypx_l, k + 1, wrow, lane);
      gather_finish(S, Bs, wrow, lane);
      gather_issue(S, xb, pypx_l, k + 1, wrow + 4, lane);
      gather_finish(S, Bs, wrow + 4, lane);
      stageA128(wb, As, (k + 1) * 256, t);
      __syncthreads();
    }
  }

  // epilogue (same fragment->C mapping as verified)
#pragma unroll
  for (int i = 0; i < 4; ++i) {
#pragma unroll
    for (int r = 0; r < 4; ++r) {
      int o = wm * 64 + i * 16 + q * 4 + r;
      float bv = bias[o];
      float* orow = out + (b * O_ + o) * HW + hw0;
#pragma unroll
      for (int j = 0; j < 2; ++j) orow[wn * 32 + j * 16 + lr] = acc[i][j][r] + bv;
    }
  }
}

// ================= fallback path (small workspace): fp32 pipeline =============
__global__ void k0_wconv(const float* __restrict__ weight, uint16_t* __restrict__ wb) {
  int idx = blockIdx.x * 256 + threadIdx.x;
  if (idx >= O_ * CK) return;
  int o = idx / CK;
  int rem = idx - o * CK;
  int k = rem >> 8;
  int c = rem & 255;
  wb[idx] = f2bf(weight[(o * C_ + c) * K_ + k]);
}

__global__ void k1_offconv(const float* __restrict__ x, const float* __restrict__ w_om,
                           const float* __restrict__ b_om, float* __restrict__ pypxmk) {
  int bx = blockIdx.x;
  int jq = bx % 7;
  int h = (bx / 7) % H_;
  int b = bx / (7 * H_);
  int t = threadIdx.x;
  int w = t & 63;
  int cs = __builtin_amdgcn_readfirstlane(t >> 6);

  float acc[4] = {0.f, 0.f, 0.f, 0.f};
  const float* xb = x + (b * C_) * HW;

  for (int ci = 0; ci < 64; ++ci) {
    int c = cs * 64 + ci;
    const float* xr = xb + c * HW;
    float xv[3][3];
#pragma unroll
    for (int r = 0; r < 3; ++r) {
      int y = h - 1 + r;
      bool yv = ((unsigned)y < 64u);
#pragma unroll
      for (int dx = 0; dx < 3; ++dx) {
        int xx = w - 1 + dx;
        bool v = yv && ((unsigned)xx < 64u);
        xv[r][dx] = v ? xr[y * 64 + xx] : 0.f;
      }
    }
    const float* wp = w_om + ((jq * 4) * C_ + c) * 9;
#pragma unroll
    for (int jj = 0; jj < 4; ++jj) {
      int j = jq * 4 + jj;
      int jeff = (j < 27) ? jj : 0;
      const float* wj = wp + jeff * (C_ * 9);
      float a = 0.f;
#pragma unroll
      for (int r = 0; r < 3; ++r)
#pragma unroll
        for (int dx = 0; dx < 3; ++dx)
          a = fmaf(xv[r][dx], wj[r * 3 + dx], a);
      acc[jj] += a;
    }
  }

  __shared__ float red[4][4][64];
#pragma unroll
  for (int jj = 0; jj < 4; ++jj) red[cs][jj][w] = acc[jj];
  __syncthreads();

  int jj = t >> 6;
  int j = jq * 4 + jj;
  if (j < 27) {
    float s = red[0][jj][w] + red[1][jj][w] + red[2][jj][w] + red[3][jj][w] + b_om[j];
    float* pyA = pypxmk;
    float* pxA = pypxmk + 147456;
    float* mkA = pypxmk + 294912;
    if (j < 18) {
      int k = j >> 1;
      int off = (b * 9 + k) * HW + h * 64 + w;
      if ((j & 1) == 0)
        pyA[off] = (float)(h - 1 + k / 3) + s;
      else
        pxA[off] = (float)(w - 1 + k % 3) + s;
    } else {
      int k = j - 18;
      mkA[(b * 9 + k) * HW + h * 64 + w] = 1.f / (1.f + __expf(-s));
    }
  }
}

__global__ void k2_fb(const float* __restrict__ x, const float* __restrict__ pypxmk,
                      uint16_t* __restrict__ cols) {
  int bx = blockIdx.x;
  int cg2 = bx & 15;
  int h = (bx >> 4) & 63;
  int b = bx >> 10;
  int t = threadIdx.x;
  int w = t & 63;
  int g = t >> 6;

  const float* pyA = pypxmk;
  const float* pxA = pypxmk + 147456;
  const float* mkA = pypxmk + 294912;

  __shared__ uint16_t tile[64 * 146];
  const float* xb = x + b * C_ * HW;
  int cbase = cg2 * 16 + g * 4;

#pragma unroll
  for (int k = 0; k < 9; ++k) {
    int poff = (b * 9 + k) * HW + h * 64 + w;
    float py = pyA[poff];
    float px = pxA[poff];
    float mk = mkA[poff];
    float fy0 = floorf(py), fx0 = floorf(px);
    float ly = py - fy0, lx = px - fx0;
    int y0 = (int)fy0, x0 = (int)fx0;
    bool vy0 = ((unsigned)y0 < 64u), vy1 = ((unsigned)(y0 + 1) < 64u);
    bool vx0 = ((unsigned)x0 < 64u), vx1 = ((unsigned)(x0 + 1) < 64u);
    float w00 = (vy0 && vx0) ? (1.f - ly) * (1.f - lx) * mk : 0.f;
    float w01 = (vy0 && vx1) ? (1.f - ly) * lx * mk : 0.f;
    float w10 = (vy1 && vx0) ? ly * (1.f - lx) * mk : 0.f;
    float w11 = (vy1 && vx1) ? ly * lx * mk : 0.f;
    bool sel0 = (x0 >= 63);
    bool sel1 = (x0 >= 0);
    float wa0 = (sel0 ? 0.f : w00) + (sel1 ? 0.f : w01);
    float wb0 = (sel0 ? w00 : 0.f) + (sel1 ? w01 : 0.f);
    float wa1 = (sel0 ? 0.f : w10) + (sel1 ? 0.f : w11);
    float wb1 = (sel0 ? w10 : 0.f) + (sel1 ? w11 : 0.f);
    int bx0 = min(max(x0, 0), 62);
    int a0 = min(max(y0, 0), 63) * 64 + bx0;
    int a1 = min(max(y0 + 1, 0), 63) * 64 + bx0;

#pragma unroll
    for (int cp = 0; cp < 2; ++cp) {
      const float* xcA = xb + (cbase + cp * 2) * HW;
      const float* xcB = xcA + HW;
      f32x2 A0 = *(const f32x2u*)&xcA[a0];
      f32x2 A1 = *(const f32x2u*)&xcA[a1];
      f32x2 B0 = *(const f32x2u*)&xcB[a0];
      f32x2 B1 = *(const f32x2u*)&xcB[a1];
      float rA = wa0 * A0.x + wb0 * A0.y + wa1 * A1.x + wb1 * A1.y;
      float rB = wa0 * B0.x + wb0 * B0.y + wa1 * B1.x + wb1 * B1.y;
      *(uint32_t*)&tile[w * 146 + k * 16 + g * 4 + cp * 2] = pk_bf16(rA, rB);
    }
  }
  __syncthreads();

#pragma unroll
  for (int it = 0; it < 18; ++it) {
    int u = t + it * 256;
    int wu = u / 72;
    int rem = u - wu * 72;
    int k = rem >> 3;
    int cd = rem & 7;
    uint32_t val = *(const uint32_t*)&tile[wu * 146 + rem * 2];
    int n = b * HW + h * 64 + wu;
    int dst = n * CK + k * 256 + cg2 * 16 + cd * 2;
    *(uint32_t*)&cols[dst] = val;
  }
}

__global__ void k3_flex(const uint16_t* __restrict__ wb, const uint16_t* __restrict__ cols,
                        const float* __restrict__ bias, float* __restrict__ out) {
  int bx = blockIdx.x;
  int mt = bx & 1;
  int nt = bx >> 1;
  int o0 = mt * 128;
  int n0 = nt * 128;
  int t = threadIdx.x;
  int lane = t & 63;
  int wid = t >> 6;
  int wm = wid >> 1, wn = wid & 1;
  int lr = lane & 15, q = lane >> 4;

  __shared__ __align__(16) uint16_t As[128 * 32];
  __shared__ __align__(16) uint16_t Bs[128 * 32];

  f32x4 acc[4][4];
  const f32x4 zero = {0.f, 0.f, 0.f, 0.f};
#pragma unroll
  for (int i = 0; i < 4; ++i)
#pragma unroll
    for (int j = 0; j < 4; ++j) acc[i][j] = zero;

  int r0 = t >> 2;
  int koff = (t & 3) * 8;
  const uint16_t* gA = wb + (o0 + r0) * CK + koff;
  const uint16_t* gB = cols + (n0 + r0) * CK + koff;

  for (int kt = 0; kt < 72; ++kt) {
    int k0 = kt * 32;
    __builtin_amdgcn_global_load_lds(
        (const __attribute__((address_space(1))) uint32_t*)(gA + k0),
        (__attribute__((address_space(3))) uint32_t*)&As[t * 8], 16, 0, 0);
    __builtin_amdgcn_global_load_lds(
        (const __attribute__((address_space(1))) uint32_t*)(gA + 64 * CK + k0),
        (__attribute__((address_space(3))) uint32_t*)&As[2048 + t * 8], 16, 0, 0);
    __builtin_amdgcn_global_load_lds(
        (const __attribute__((address_space(1))) uint32_t*)(gB + k0),
        (__attribute__((address_space(3))) uint32_t*)&Bs[t * 8], 16, 0, 0);
    __builtin_amdgcn_global_load_lds(
        (const __attribute__((address_space(1))) uint32_t*)(gB + 64 * CK + k0),
        (__attribute__((address_space(3))) uint32_t*)&Bs[2048 + t * 8], 16, 0, 0);
    __syncthreads();

    bf16x8 aF[4], bF[4];
#pragma unroll
    for (int i = 0; i < 4; ++i)
      aF[i] = *(const bf16x8*)&As[(wm * 64 + i * 16 + lr) * 32 + q * 8];
#pragma unroll
    for (int j = 0; j < 4; ++j)
      bF[j] = *(const bf16x8*)&Bs[(wn * 64 + j * 16 + lr) * 32 + q * 8];
#pragma unroll
    for (int i = 0; i < 4; ++i)
#pragma unroll
      for (int j = 0; j < 4; ++j)
        acc[i][j] = __builtin_amdgcn_mfma_f32_16x16x32_bf16(aF[i], bF[j], acc[i][j], 0, 0, 0);
    __syncthreads();
  }

  int bb = n0 >> 12;
  int hw0 = n0 & 4095;
#pragma unroll
  for (int i = 0; i < 4; ++i) {
#pragma unroll
    for (int r = 0; r < 4; ++r) {
      int o = o0 + wm * 64 + i * 16 + q * 4 + r;
      float bv = bias[o];
      float* orow = out + (bb * O_ + o) * HW + hw0;
#pragma unroll
      for (int j = 0; j < 4; ++j) orow[wn * 64 + j * 16 + lr] = acc[i][j][r] + bv;
    }
  }
}

extern "C" void kernel_launch(void* const* d_in, const int* in_sizes, int n_in,
                              void* d_out, int out_size, void* d_ws, size_t ws_size,
                              hipStream_t stream) {
  const float* x = (const float*)d_in[0];
  const float* w_om = (const float*)d_in[1];
  const float* b_om = (const float*)d_in[2];
  const float* weight = (const float*)d_in[3];
  const float* bias = (const float*)d_in[4];
  float* out = (float*)d_out;

  char* ws = (char*)d_ws;
  uint16_t* wb = (uint16_t*)ws;                   // 1,179,648 B
  uint16_t* womb = (uint16_t*)(ws + 1179648);     // 147,456 B    -> 1,327,104
  uint16_t* xT = (uint16_t*)(ws + 1327104);       // 8,388,608 B  -> 9,715,712

  if (ws_size >= 11485184ull) {
    // 2-dispatch pipeline: prep -> fused {offset conv + gather + GEMM}, BK=128
    hipLaunchKernelGGL(kA_prep, dim3(1312), dim3(256), 0, stream, weight, w_om, x, wb, womb, xT);
    hipLaunchKernelGGL(k123, dim3(256), dim3(512), 0, stream, wb, womb, xT, b_om, bias, out);
  } else {
    // fallback: fp32 pipeline + single-pass GEMM (needs 78.4 MB)
    float* pypx_fb = (float*)(ws + 1179648);
    uint16_t* colsf = (uint16_t*)(ws + 2949120);
    hipLaunchKernelGGL(k0_wconv, dim3(2304), dim3(256), 0, stream, weight, wb);
    hipLaunchKernelGGL(k1_offconv, dim3(4 * 64 * 7), dim3(256), 0, stream, x, w_om, b_om, pypx_fb);
    hipLaunchKernelGGL(k2_fb, dim3(4 * 64 * 16), dim3(256), 0, stream, x, pypx_fb, colsf);
    hipLaunchKernelGGL(k3_flex, dim3(256), dim3(256), 0, stream, wb, colsf, bias, out);
  }
}

// Round 12
// 147.075 us; speedup vs baseline: 1.0430x; 1.0163x over previous
//
#include <hip/hip_runtime.h>
#include <stdint.h>

#define B_ 4
#define C_ 256
#define H_ 64
#define W_ 64
#define O_ 256
#define K_ 9
#define CK 2304     // K_*C_  (ck = k*256 + c, k-major)
#define HW 4096
#define NTOT 16384  // B_*HW

typedef __bf16 bf16x8 __attribute__((ext_vector_type(8)));
typedef __bf16 bf16x4 __attribute__((ext_vector_type(4)));
typedef float f32x4 __attribute__((ext_vector_type(4)));
typedef float f32x2 __attribute__((ext_vector_type(2)));
typedef f32x2 __attribute__((aligned(4))) f32x2u;

__device__ __forceinline__ uint16_t f2bf(float f) {
  uint32_t u = __builtin_bit_cast(uint32_t, f);
  return (uint16_t)((u + 0x7FFFu + ((u >> 16) & 1u)) >> 16);
}

__device__ __forceinline__ uint32_t pk_bf16(float a, float b) {
  uint16_t lo = __builtin_bit_cast(uint16_t, (__bf16)a);
  uint16_t hi = __builtin_bit_cast(uint16_t, (__bf16)b);
  return (uint32_t)lo | ((uint32_t)hi << 16);
}

// ======== kA v3: wb/womb sections unchanged (coalesced, verified). Transpose
// rewritten: float LDS tile [64][65] (bank = (spatial+channel)%32, 2-way both
// sides = free, vs 8-way before), global reads 4x float4/thread (vs 16 dwords).
__global__ void kA_prep(const float* __restrict__ weight, const float* __restrict__ w_om,
                        const float* __restrict__ x, uint16_t* __restrict__ wb,
                        uint16_t* __restrict__ womb, uint16_t* __restrict__ xT) {
  int bx = blockIdx.x;
  int t = threadIdx.x;
  if (bx < 256) {
    int o = bx, c = t;
    const float* wp = weight + (o * 256 + c) * 9;
#pragma unroll
    for (int k = 0; k < 9; ++k) wb[o * CK + k * 256 + c] = f2bf(wp[k]);
  } else if (bx < 283) {
    int j = bx - 256, c = t;  // j 0..26
    const float* wp = w_om + (j * 256 + c) * 9;
#pragma unroll
    for (int k = 0; k < 9; ++k) womb[j * CK + k * 256 + c] = f2bf(wp[k]);
  } else if (bx < 288) {
    int j = 27 + (bx - 283), c = t;  // zero rows 27..31 (row 31 = zrow)
#pragma unroll
    for (int k = 0; k < 9; ++k) womb[j * CK + k * 256 + c] = 0;
  } else {
    int bxl = bx - 288;
    int ct = bxl & 3;
    int hwt = (bxl >> 2) & 63;
    int b = bxl >> 8;

    __shared__ __align__(16) float tf[64 * 65];  // [spatial l][channel c], stride 65

    // read: thread t -> channel row cr = t>>2 (0..63), quarter q4 = t&3 (16 floats)
    int cr = t >> 2, q4 = t & 3;
    const float* xr = x + ((size_t)(b * 256 + ct * 64 + cr)) * HW + hwt * 64 + q4 * 16;
#pragma unroll
    for (int i = 0; i < 4; ++i) {
      f32x4 v = *(const f32x4*)&xr[i * 4];
#pragma unroll
      for (int j = 0; j < 4; ++j) tf[(q4 * 16 + i * 4 + j) * 65 + cr] = v[j];
    }
    __syncthreads();

    // write: thread t -> spatial row hw = t>>2, c8 = (t&3)*8; convert + 2x16B store
    int hw = t >> 2, c8 = (t & 3) * 8;
    uint16_t tmp[16];
#pragma unroll
    for (int j = 0; j < 8; ++j) tmp[j] = f2bf(tf[hw * 65 + c8 + j]);
#pragma unroll
    for (int j = 0; j < 8; ++j) tmp[8 + j] = f2bf(tf[hw * 65 + c8 + 32 + j]);
    uint16_t* dst = xT + ((size_t)b << 20) + (size_t)(hwt * 64 + hw) * 256 + ct * 64;
    *(uint4*)&dst[c8] = *(const uint4*)&tmp[0];
    *(uint4*)&dst[c8 + 32] = *(const uint4*)&tmp[8];
  }
}

// ======== k123 (R8-exact, best verified 77.8 us): prologue = LDS-staged offset-conv
// GEMM -> pypx_l in LDS; phase C = R7/R2 fused gather + GEMM, BK=64 As dbuf. ========

struct GatherState {
  float wa0[4], wb0[4], wa1[4], wb1[4];
  bf16x4 r00[4], r01[4], r10[4], r11[4];
};

__device__ __forceinline__ void gather_issue(GatherState& S, const uint16_t* __restrict__ xb,
                                             const float* pypx_l,  // LDS [3][9][64]
                                             int kg, int rbase, int lane) {
#pragma unroll
  for (int j = 0; j < 4; ++j) {
    int nrow = rbase + j;
    float py = pypx_l[(0 * 9 + kg) * 64 + nrow];
    float px = pypx_l[(1 * 9 + kg) * 64 + nrow];
    float mk = pypx_l[(2 * 9 + kg) * 64 + nrow];
    float fy0 = floorf(py), fx0 = floorf(px);
    float ly = py - fy0, lx = px - fx0;
    int y0 = (int)fy0, x0 = (int)fx0;
    bool vy0 = ((unsigned)y0 < 64u), vy1 = ((unsigned)(y0 + 1) < 64u);
    bool vx0 = ((unsigned)x0 < 64u), vx1 = ((unsigned)(x0 + 1) < 64u);
    float w00 = (vy0 && vx0) ? (1.f - ly) * (1.f - lx) * mk : 0.f;
    float w01 = (vy0 && vx1) ? (1.f - ly) * lx * mk : 0.f;
    float w10 = (vy1 && vx0) ? ly * (1.f - lx) * mk : 0.f;
    float w11 = (vy1 && vx1) ? ly * lx * mk : 0.f;
    bool sel0 = (x0 >= 63);
    bool sel1 = (x0 >= 0);
    S.wa0[j] = (sel0 ? 0.f : w00) + (sel1 ? 0.f : w01);
    S.wb0[j] = (sel0 ? w00 : 0.f) + (sel1 ? w01 : 0.f);
    S.wa1[j] = (sel0 ? 0.f : w10) + (sel1 ? 0.f : w11);
    S.wb1[j] = (sel0 ? w10 : 0.f) + (sel1 ? w11 : 0.f);
    int bx0 = min(max(x0, 0), 62);
    int a0 = min(max(y0, 0), 63) * 64 + bx0;
    int a1 = min(max(y0 + 1, 0), 63) * 64 + bx0;
    S.r00[j] = *(const bf16x4*)&xb[a0 * 256 + lane * 4];
    S.r01[j] = *(const bf16x4*)&xb[a0 * 256 + 256 + lane * 4];
    S.r10[j] = *(const bf16x4*)&xb[a1 * 256 + lane * 4];
    S.r11[j] = *(const bf16x4*)&xb[a1 * 256 + 256 + lane * 4];
  }
}

__device__ __forceinline__ void gather_finish(const GatherState& S, uint16_t* bslab,
                                              int rbase, int lane) {
#pragma unroll
  for (int j = 0; j < 4; ++j) {
    int nrow = rbase + j;
    float v[4];
#pragma unroll
    for (int i = 0; i < 4; ++i)
      v[i] = S.wa0[j] * (float)S.r00[j][i] + S.wb0[j] * (float)S.r01[j][i] +
             S.wa1[j] * (float)S.r10[j][i] + S.wb1[j] * (float)S.r11[j][i];
    uint2 pk;
    pk.x = pk_bf16(v[0], v[1]);
    pk.y = pk_bf16(v[2], v[3]);
    int chunk = lane >> 1;                               // 0..31 (8-elem chunks)
    int chs = (chunk & 24) | ((chunk & 7) ^ (nrow & 7)); // XOR swizzle, involution
    *(uint2*)&bslab[nrow * 256 + chs * 8 + (lane & 1) * 4] = pk;
  }
}

__device__ __forceinline__ void stageA(const uint16_t* __restrict__ wb, uint16_t* asbuf,
                                       int kbase, int t) {
#pragma unroll
  for (int i = 0; i < 4; ++i) {
    int rr = i * 64 + (t >> 3);
    const uint16_t* src = wb + rr * CK + kbase + (((t & 7) ^ (rr & 7)) << 3);
    __builtin_amdgcn_global_load_lds(
        (const __attribute__((address_space(1))) uint32_t*)src,
        (__attribute__((address_space(3))) uint32_t*)&asbuf[i * 4096 + t * 8], 16, 0, 0);
  }
}

__device__ __forceinline__ void mma_step(const uint16_t* AsP, const uint16_t* BsP,
                                         f32x4 acc[4][2], int wm, int wn, int lr, int q,
                                         int kt2) {
#pragma unroll
  for (int kc = 0; kc < 2; ++kc) {
    bf16x8 aF[4], bF[2];
#pragma unroll
    for (int i = 0; i < 4; ++i) {
      int row = wm * 64 + i * 16 + lr;
      aF[i] = *(const bf16x8*)&AsP[row * 64 + (((kc * 4 + q) ^ (row & 7)) << 3)];
    }
#pragma unroll
    for (int j = 0; j < 2; ++j) {
      int row = wn * 32 + j * 16 + lr;
      int kidx = kt2 * 8 + kc * 4 + q;  // 0..31
      int chs = (kidx & 24) | ((kidx & 7) ^ (row & 7));
      bF[j] = *(const bf16x8*)&BsP[row * 256 + chs * 8];
    }
#pragma unroll
    for (int i = 0; i < 4; ++i)
#pragma unroll
      for (int j = 0; j < 2; ++j)
        acc[i][j] = __builtin_amdgcn_mfma_f32_16x16x32_bf16(aF[i], bF[j], acc[i][j], 0, 0, 0);
  }
}

__global__ __launch_bounds__(512, 2) void k123(const uint16_t* __restrict__ wb,
                                               const uint16_t* __restrict__ womb,
                                               const uint16_t* __restrict__ xT,
                                               const float* __restrict__ b_om,
                                               const float* __restrict__ bias,
                                               float* __restrict__ out) {
  __shared__ __align__(16) uint16_t As[2][16384];  // 2 x 32 KB
  __shared__ __align__(16) uint16_t Bs[16384];     // 32 KB (single buffer)
  __shared__ float pypx_l[3 * 9 * 64];             // 6.75 KB: [py|px|mk][k][nn]

  int t = threadIdx.x;
  int lane = t & 63;
  int wid = __builtin_amdgcn_readfirstlane(t >> 6);
  int lr = lane & 15, q = lane >> 4;
  int bx = blockIdx.x;
  int swz = (bx & 7) * 32 + (bx >> 3);  // bijective XCD swizzle (256 % 8 == 0)
  int n0 = swz * 64;
  int b = n0 >> 12;
  int hw0 = n0 & 4095;
  const uint16_t* xb = xT + ((size_t)b << 20);

  // ====== prologue (R8-verified): offset conv as LDS-staged GEMM -> pypx_l ======
  {
    uint16_t* Apro = As[0];  // 16 KB of As[0] used as [32 j][256 c]
    int jh = wid >> 2, ng = wid & 3;
    const uint16_t* zrow = womb + 31 * CK;  // 2304 zeros
    f32x4 accp = {0.f, 0.f, 0.f, 0.f};

    for (int k = 0; k < 9; ++k) {
      int dy = k / 3 - 1, dx = k - (k / 3) * 3 - 1;
      // stage A: womb k-slice, 2 shots x 512 thr x 16 B = 16 KB, coalesced
#pragma unroll
      for (int i = 0; i < 2; ++i) {
        int id = i * 512 + t;
        int row = id >> 5, c5 = id & 31;
        int cs = (c5 & 24) | ((c5 & 7) ^ (row & 7));
        const uint16_t* src = womb + row * CK + k * 256 + cs * 8;
        __builtin_amdgcn_global_load_lds(
            (const __attribute__((address_space(1))) uint32_t*)src,
            (__attribute__((address_space(3))) uint32_t*)&Apro[row * 256 + c5 * 8], 16, 0, 0);
      }
      // stage B: identity-offset patch slab, 4 shots x 8 KB = 32 KB, coalesced
#pragma unroll
      for (int i = 0; i < 4; ++i) {
        int id = i * 512 + t;
        int nrow = id >> 5, c5 = id & 31;
        int hw = (n0 + nrow) & 4095;
        int y = hw >> 6, xx = hw & 63;
        int ny = y + dy, nx = xx + dx;
        bool valid = ((unsigned)ny < 64u) && ((unsigned)nx < 64u);
        int row_g = (ny << 6) + nx;
        int cs = (c5 & 24) | ((c5 & 7) ^ (nrow & 7));
        const uint16_t* src = valid ? (xb + row_g * 256 + cs * 8) : (zrow + cs * 8);
        __builtin_amdgcn_global_load_lds(
            (const __attribute__((address_space(1))) uint32_t*)src,
            (__attribute__((address_space(3))) uint32_t*)&Bs[nrow * 256 + c5 * 8], 16, 0, 0);
      }
      __syncthreads();
      // 8 MFMA: j-tile jh (16 j) x n-tile ng (16 n), K=256 over c
#pragma unroll
      for (int kt = 0; kt < 8; ++kt) {
        int kidx = kt * 4 + q;
        int arow = jh * 16 + lr;
        int achs = (kidx & 24) | ((kidx & 7) ^ (arow & 7));
        bf16x8 aF = *(const bf16x8*)&Apro[arow * 256 + achs * 8];
        int brow = ng * 16 + lr;
        int bchs = (kidx & 24) | ((kidx & 7) ^ (brow & 7));
        bf16x8 bF = *(const bf16x8*)&Bs[brow * 256 + bchs * 8];
        accp = __builtin_amdgcn_mfma_f32_16x16x32_bf16(aF, bF, accp, 0, 0, 0);
      }
      __syncthreads();
    }

    // write py/px/mk for own (j-tile, n-tile): j = jh*16 + q*4 + r, n = ng*16 + lr
    int nn = ng * 16 + lr;
    int hwp = (n0 + nn) & 4095;
    int yp = hwp >> 6, xp = hwp & 63;
#pragma unroll
    for (int r = 0; r < 4; ++r) {
      int j = jh * 16 + q * 4 + r;
      if (j < 27) {
        float v = accp[r] + b_om[j];
        if (j < 18) {
          int k = j >> 1;
          if ((j & 1) == 0)
            pypx_l[(0 * 9 + k) * 64 + nn] = (float)(yp - 1 + k / 3) + v;
          else
            pypx_l[(1 * 9 + k) * 64 + nn] = (float)(xp - 1 + k % 3) + v;
        } else {
          pypx_l[(2 * 9 + (j - 18)) * 64 + nn] = 1.f / (1.f + __expf(-v));
        }
      }
    }
    __syncthreads();
  }

  // ============ phase C: fused gather + GEMM (verbatim R7/R8 structure) ============
  f32x4 acc[4][2];
  const f32x4 zero = {0.f, 0.f, 0.f, 0.f};
#pragma unroll
  for (int i = 0; i < 4; ++i)
#pragma unroll
    for (int j = 0; j < 2; ++j) acc[i][j] = zero;

  int wm = wid >> 1, wn = wid & 1;
  GatherState S;
  int wrow = wid * 8;  // this wave's 8 gather rows

  // prologue: gather k=0 slab into Bs; stage (k=0, phase 0) into As[0]
  gather_issue(S, xb, pypx_l, 0, wrow, lane);
  gather_finish(S, Bs, wrow, lane);
  gather_issue(S, xb, pypx_l, 0, wrow + 4, lane);
  gather_finish(S, Bs, wrow + 4, lane);
  stageA(wb, As[0], 0, t);
  __syncthreads();

  for (int k = 0; k < 9; ++k) {
    for (int kt2 = 0; kt2 < 4; ++kt2) {
      // m97 pattern: stage next sub-slab into the OTHER As buffer, read current
      if (!(k == 8 && kt2 == 3)) {
        int kb2 = (kt2 == 3) ? (k + 1) * 256 : k * 256 + (kt2 + 1) * 64;
        stageA(wb, As[(kt2 + 1) & 1], kb2, t);
      }
      mma_step(As[kt2 & 1], Bs, acc, wm, wn, lr, q, kt2);
      __syncthreads();
    }
    // isolated gather region for slab k+1 (writes after all reads, barriers around)
    if (k < 8) {
      gather_issue(S, xb, pypx_l, k + 1, wrow, lane);
      gather_finish(S, Bs, wrow, lane);
      gather_issue(S, xb, pypx_l, k + 1, wrow + 4, lane);
      gather_finish(S, Bs, wrow + 4, lane);
      __syncthreads();
    }
  }

  // epilogue (same fragment->C mapping as verified)
#pragma unroll
  for (int i = 0; i < 4; ++i) {
#pragma unroll
    for (int r = 0; r < 4; ++r) {
      int o = wm * 64 + i * 16 + q * 4 + r;
      float bv = bias[o];
      float* orow = out + (b * O_ + o) * HW + hw0;
#pragma unroll
      for (int j = 0; j < 2; ++j) orow[wn * 32 + j * 16 + lr] = acc[i][j][r] + bv;
    }
  }
}

// ================= fallback path (small workspace): fp32 pipeline =============
__global__ void k0_wconv(const float* __restrict__ weight, uint16_t* __restrict__ wb) {
  int idx = blockIdx.x * 256 + threadIdx.x;
  if (idx >= O_ * CK) return;
  int o = idx / CK;
  int rem = idx - o * CK;
  int k = rem >> 8;
  int c = rem & 255;
  wb[idx] = f2bf(weight[(o * C_ + c) * K_ + k]);
}

__global__ void k1_offconv(const float* __restrict__ x, const float* __restrict__ w_om,
                           const float* __restrict__ b_om, float* __restrict__ pypxmk) {
  int bx = blockIdx.x;
  int jq = bx % 7;
  int h = (bx / 7) % H_;
  int b = bx / (7 * H_);
  int t = threadIdx.x;
  int w = t & 63;
  int cs = __builtin_amdgcn_readfirstlane(t >> 6);

  float acc[4] = {0.f, 0.f, 0.f, 0.f};
  const float* xb = x + (b * C_) * HW;

  for (int ci = 0; ci < 64; ++ci) {
    int c = cs * 64 + ci;
    const float* xr = xb + c * HW;
    float xv[3][3];
#pragma unroll
    for (int r = 0; r < 3; ++r) {
      int y = h - 1 + r;
      bool yv = ((unsigned)y < 64u);
#pragma unroll
      for (int dx = 0; dx < 3; ++dx) {
        int xx = w - 1 + dx;
        bool v = yv && ((unsigned)xx < 64u);
        xv[r][dx] = v ? xr[y * 64 + xx] : 0.f;
      }
    }
    const float* wp = w_om + ((jq * 4) * C_ + c) * 9;
#pragma unroll
    for (int jj = 0; jj < 4; ++jj) {
      int j = jq * 4 + jj;
      int jeff = (j < 27) ? jj : 0;
      const float* wj = wp + jeff * (C_ * 9);
      float a = 0.f;
#pragma unroll
      for (int r = 0; r < 3; ++r)
#pragma unroll
        for (int dx = 0; dx < 3; ++dx)
          a = fmaf(xv[r][dx], wj[r * 3 + dx], a);
      acc[jj] += a;
    }
  }

  __shared__ float red[4][4][64];
#pragma unroll
  for (int jj = 0; jj < 4; ++jj) red[cs][jj][w] = acc[jj];
  __syncthreads();

  int jj = t >> 6;
  int j = jq * 4 + jj;
  if (j < 27) {
    float s = red[0][jj][w] + red[1][jj][w] + red[2][jj][w] + red[3][jj][w] + b_om[j];
    float* pyA = pypxmk;
    float* pxA = pypxmk + 147456;
    float* mkA = pypxmk + 294912;
    if (j < 18) {
      int k = j >> 1;
      int off = (b * 9 + k) * HW + h * 64 + w;
      if ((j & 1) == 0)
        pyA[off] = (float)(h - 1 + k / 3) + s;
      else
        pxA[off] = (float)(w - 1 + k % 3) + s;
    } else {
      int k = j - 18;
      mkA[(b * 9 + k) * HW + h * 64 + w] = 1.f / (1.f + __expf(-s));
    }
  }
}

__global__ void k2_fb(const float* __restrict__ x, const float* __restrict__ pypxmk,
                      uint16_t* __restrict__ cols) {
  int bx = blockIdx.x;
  int cg2 = bx & 15;
  int h = (bx >> 4) & 63;
  int b = bx >> 10;
  int t = threadIdx.x;
  int w = t & 63;
  int g = t >> 6;

  const float* pyA = pypxmk;
  const float* pxA = pypxmk + 147456;
  const float* mkA = pypxmk + 294912;

  __shared__ uint16_t tile[64 * 146];
  const float* xb = x + b * C_ * HW;
  int cbase = cg2 * 16 + g * 4;

#pragma unroll
  for (int k = 0; k < 9; ++k) {
    int poff = (b * 9 + k) * HW + h * 64 + w;
    float py = pyA[poff];
    float px = pxA[poff];
    float mk = mkA[poff];
    float fy0 = floorf(py), fx0 = floorf(px);
    float ly = py - fy0, lx = px - fx0;
    int y0 = (int)fy0, x0 = (int)fx0;
    bool vy0 = ((unsigned)y0 < 64u), vy1 = ((unsigned)(y0 + 1) < 64u);
    bool vx0 = ((unsigned)x0 < 64u), vx1 = ((unsigned)(x0 + 1) < 64u);
    float w00 = (vy0 && vx0) ? (1.f - ly) * (1.f - lx) * mk : 0.f;
    float w01 = (vy0 && vx1) ? (1.f - ly) * lx * mk : 0.f;
    float w10 = (vy1 && vx0) ? ly * (1.f - lx) * mk : 0.f;
    float w11 = (vy1 && vx1) ? ly * lx * mk : 0.f;
    bool sel0 = (x0 >= 63);
    bool sel1 = (x0 >= 0);
    float wa0 = (sel0 ? 0.f : w00) + (sel1 ? 0.f : w01);
    float wb0 = (sel0 ? w00 : 0.f) + (sel1 ? w01 : 0.f);
    float wa1 = (sel0 ? 0.f : w10) + (sel1 ? 0.f : w11);
    float wb1 = (sel0 ? w10 : 0.f) + (sel1 ? w11 : 0.f);
    int bx0 = min(max(x0, 0), 62);
    int a0 = min(max(y0, 0), 63) * 64 + bx0;
    int a1 = min(max(y0 + 1, 0), 63) * 64 + bx0;

#pragma unroll
    for (int cp = 0; cp < 2; ++cp) {
      const float* xcA = xb + (cbase + cp * 2) * HW;
      const float* xcB = xcA + HW;
      f32x2 A0 = *(const f32x2u*)&xcA[a0];
      f32x2 A1 = *(const f32x2u*)&xcA[a1];
      f32x2 B0 = *(const f32x2u*)&xcB[a0];
      f32x2 B1 = *(const f32x2u*)&xcB[a1];
      float rA = wa0 * A0.x + wb0 * A0.y + wa1 * A1.x + wb1 * A1.y;
      float rB = wa0 * B0.x + wb0 * B0.y + wa1 * B1.x + wb1 * B1.y;
      *(uint32_t*)&tile[w * 146 + k * 16 + g * 4 + cp * 2] = pk_bf16(rA, rB);
    }
  }
  __syncthreads();

#pragma unroll
  for (int it = 0; it < 18; ++it) {
    int u = t + it * 256;
    int wu = u / 72;
    int rem = u - wu * 72;
    int k = rem >> 3;
    int cd = rem & 7;
    uint32_t val = *(const uint32_t*)&tile[wu * 146 + rem * 2];
    int n = b * HW + h * 64 + wu;
    int dst = n * CK + k * 256 + cg2 * 16 + cd * 2;
    *(uint32_t*)&cols[dst] = val;
  }
}

__global__ void k3_flex(const uint16_t* __restrict__ wb, const uint16_t* __restrict__ cols,
                        const float* __restrict__ bias, float* __restrict__ out) {
  int bx = blockIdx.x;
  int mt = bx & 1;
  int nt = bx >> 1;
  int o0 = mt * 128;
  int n0 = nt * 128;
  int t = threadIdx.x;
  int lane = t & 63;
  int wid = t >> 6;
  int wm = wid >> 1, wn = wid & 1;
  int lr = lane & 15, q = lane >> 4;

  __shared__ __align__(16) uint16_t As[128 * 32];
  __shared__ __align__(16) uint16_t Bs[128 * 32];

  f32x4 acc[4][4];
  const f32x4 zero = {0.f, 0.f, 0.f, 0.f};
#pragma unroll
  for (int i = 0; i < 4; ++i)
#pragma unroll
    for (int j = 0; j < 4; ++j) acc[i][j] = zero;

  int r0 = t >> 2;
  int koff = (t & 3) * 8;
  const uint16_t* gA = wb + (o0 + r0) * CK + koff;
  const uint16_t* gB = cols + (n0 + r0) * CK + koff;

  for (int kt = 0; kt < 72; ++kt) {
    int k0 = kt * 32;
    __builtin_amdgcn_global_load_lds(
        (const __attribute__((address_space(1))) uint32_t*)(gA + k0),
        (__attribute__((address_space(3))) uint32_t*)&As[t * 8], 16, 0, 0);
    __builtin_amdgcn_global_load_lds(
        (const __attribute__((address_space(1))) uint32_t*)(gA + 64 * CK + k0),
        (__attribute__((address_space(3))) uint32_t*)&As[2048 + t * 8], 16, 0, 0);
    __builtin_amdgcn_global_load_lds(
        (const __attribute__((address_space(1))) uint32_t*)(gB + k0),
        (__attribute__((address_space(3))) uint32_t*)&Bs[t * 8], 16, 0, 0);
    __builtin_amdgcn_global_load_lds(
        (const __attribute__((address_space(1))) uint32_t*)(gB + 64 * CK + k0),
        (__attribute__((address_space(3))) uint32_t*)&Bs[2048 + t * 8], 16, 0, 0);
    __syncthreads();

    bf16x8 aF[4], bF[4];
#pragma unroll
    for (int i = 0; i < 4; ++i)
      aF[i] = *(const bf16x8*)&As[(wm * 64 + i * 16 + lr) * 32 + q * 8];
#pragma unroll
    for (int j = 0; j < 4; ++j)
      bF[j] = *(const bf16x8*)&Bs[(wn * 64 + j * 16 + lr) * 32 + q * 8];
#pragma unroll
    for (int i = 0; i < 4; ++i)
#pragma unroll
      for (int j = 0; j < 4; ++j)
        acc[i][j] = __builtin_amdgcn_mfma_f32_16x16x32_bf16(aF[i], bF[j], acc[i][j], 0, 0, 0);
    __syncthreads();
  }

  int bb = n0 >> 12;
  int hw0 = n0 & 4095;
#pragma unroll
  for (int i = 0; i < 4; ++i) {
#pragma unroll
    for (int r = 0; r < 4; ++r) {
      int o = o0 + wm * 64 + i * 16 + q * 4 + r;
      float bv = bias[o];
      float* orow = out + (bb * O_ + o) * HW + hw0;
#pragma unroll
      for (int j = 0; j < 4; ++j) orow[wn * 64 + j * 16 + lr] = acc[i][j][r] + bv;
    }
  }
}

extern "C" void kernel_launch(void* const* d_in, const int* in_sizes, int n_in,
                              void* d_out, int out_size, void* d_ws, size_t ws_size,
                              hipStream_t stream) {
  const float* x = (const float*)d_in[0];
  const float* w_om = (const float*)d_in[1];
  const float* b_om = (const float*)d_in[2];
  const float* weight = (const float*)d_in[3];
  const float* bias = (const float*)d_in[4];
  float* out = (float*)d_out;

  char* ws = (char*)d_ws;
  uint16_t* wb = (uint16_t*)ws;                   // 1,179,648 B
  uint16_t* womb = (uint16_t*)(ws + 1179648);     // 147,456 B    -> 1,327,104
  uint16_t* xT = (uint16_t*)(ws + 1327104);       // 8,388,608 B  -> 9,715,712

  if (ws_size >= 11485184ull) {
    // 2-dispatch pipeline: prep (v3 transpose) -> fused {offset conv + gather + GEMM}
    hipLaunchKernelGGL(kA_prep, dim3(1312), dim3(256), 0, stream, weight, w_om, x, wb, womb, xT);
    hipLaunchKernelGGL(k123, dim3(256), dim3(512), 0, stream, wb, womb, xT, b_om, bias, out);
  } else {
    // fallback: fp32 pipeline + single-pass GEMM (needs 78.4 MB)
    float* pypx_fb = (float*)(ws + 1179648);
    uint16_t* colsf = (uint16_t*)(ws + 2949120);
    hipLaunchKernelGGL(k0_wconv, dim3(2304), dim3(256), 0, stream, weight, wb);
    hipLaunchKernelGGL(k1_offconv, dim3(4 * 64 * 7), dim3(256), 0, stream, x, w_om, b_om, pypx_fb);
    hipLaunchKernelGGL(k2_fb, dim3(4 * 64 * 16), dim3(256), 0, stream, x, pypx_fb, colsf);
    hipLaunchKernelGGL(k3_flex, dim3(256), dim3(256), 0, stream, wb, colsf, bias, out);
  }
}